// Round 9
// baseline (368.730 us; speedup 1.0000x reference)
//
#include <hip/hip_runtime.h>
#include <math.h>

#define DIM 128

typedef __attribute__((ext_vector_type(8))) short bf16x8;
typedef __attribute__((ext_vector_type(4))) float f32x4;

__device__ __forceinline__ ushort f2bf(float f) {  // RTNE
  unsigned u = __float_as_uint(f);
  return (ushort)((u + 0x7FFFu + ((u >> 16) & 1u)) >> 16);
}
__device__ __forceinline__ float bf2f(ushort h) {
  return __uint_as_float(((unsigned)h) << 16);
}

// ================= CSR build via bucketed counting sort (NO global atomics) =================
// bucket = dst >> 7 (128 nodes/bucket); unstable binning (aggregation order-free).

// ---- K_A: per-block bucket histogram || x->bf16 cast || W1/W2 wsplit ----
__global__ __launch_bounds__(256) void count_cast_kernel(
    const int* __restrict__ dst, unsigned* __restrict__ counts, int E, int NB, int NBUCK,
    const float* __restrict__ x, ushort* __restrict__ xh, long total_f,
    const float* __restrict__ W1l, const float* __restrict__ W1r,
    const float* __restrict__ W2l, const float* __restrict__ W2r,
    ushort* __restrict__ tabs, int CB) {
  __shared__ unsigned hist[1024];
  const int tid = threadIdx.x;
  int bid = blockIdx.x;
  if (bid < NB) {  // count role: 2048 edges per block
    for (int i = tid; i < NBUCK; i += 256) hist[i] = 0u;
    __syncthreads();
    long base = (long)bid * 2048;
#pragma unroll
    for (int c = 0; c < 8; ++c) {
      long e = base + c * 256 + tid;
      if (e < E) atomicAdd(&hist[((unsigned)dst[e]) >> 7], 1u);
    }
    __syncthreads();
    for (int i = tid; i < NBUCK; i += 256)
      counts[(size_t)bid * NBUCK + i] = hist[i];
    return;
  }
  int aid = bid - NB;
  if (aid < CB) {  // cast role: 2048 float4 per block
    long i = ((long)aid * 2048 + tid) * 4;
    for (int c = 0; c < 8; ++c, i += 1024) {
      if (i >= total_f) break;
      float4 v = *(const float4*)(x + i);
      uint2 Hh;
      Hh.x = (unsigned)f2bf(v.x) | ((unsigned)f2bf(v.y) << 16);
      Hh.y = (unsigned)f2bf(v.z) | ((unsigned)f2bf(v.w) << 16);
      *(uint2*)(xh + i) = Hh;
    }
    return;
  }
  int aid2 = aid - CB;  // wsplit role: 256 blocks, 4 mats transposed+cast
  if (aid2 < 256) {
    int m = aid2 >> 6;
    const float* W = (m == 0) ? W1l : (m == 1) ? W1r : (m == 2) ? W2l : W2r;
    ushort* Ht = tabs + (size_t)m * 16384;
    int idx = (aid2 & 63) * 256 + tid;
    int k = idx >> 7, n = idx & 127;
    Ht[n * DIM + k] = f2bf(W[idx]);
  }
}

// ---- K_B: per-bucket column scan of counts[block][bucket] (one wave per bucket) ----
__global__ __launch_bounds__(256) void colscan_kernel(unsigned* __restrict__ counts,
                                                      unsigned* __restrict__ totals,
                                                      int NB, int NBUCK) {
  int wid = (blockIdx.x << 2) + (threadIdx.x >> 6);
  int lane = threadIdx.x & 63;
  if (wid >= NBUCK) return;
  unsigned carry = 0u;
  for (int k0 = 0; k0 < NB; k0 += 64) {
    int k = k0 + lane;
    unsigned v = (k < NB) ? counts[(size_t)k * NBUCK + wid] : 0u;
    unsigned s = v;
#pragma unroll
    for (int o = 1; o < 64; o <<= 1) {
      unsigned t = __shfl_up(s, o, 64);
      if (lane >= o) s += t;
    }
    if (k < NB) counts[(size_t)k * NBUCK + wid] = carry + s - v;  // exclusive
    carry += __shfl(s, 63, 64);
  }
  if (lane == 0) totals[wid] = carry;
}

// ---- K_C: scan bucket totals -> bucket bases; totals[NBUCK] = E ----
__global__ __launch_bounds__(256) void totscan_kernel(unsigned* __restrict__ totals,
                                                      int NBUCK, int E) {
  __shared__ unsigned s[256];
  __shared__ unsigned carry;
  if (threadIdx.x == 0) carry = 0u;
  __syncthreads();
  for (int base = 0; base < NBUCK; base += 256) {
    int i = base + threadIdx.x;
    unsigned v = (i < NBUCK) ? totals[i] : 0u;
    s[threadIdx.x] = v;
    __syncthreads();
#pragma unroll
    for (int d = 1; d < 256; d <<= 1) {
      unsigned t = (threadIdx.x >= d) ? s[threadIdx.x - d] : 0u;
      __syncthreads();
      s[threadIdx.x] += t;
      __syncthreads();
    }
    if (i < NBUCK) totals[i] = carry + s[threadIdx.x] - v;
    __syncthreads();
    if (threadIdx.x == 0) carry += s[255];
    __syncthreads();
  }
  if (threadIdx.x == 0) totals[NBUCK] = (unsigned)E;
}

// ---- K_D: scatter PACKED (src<<7 | dst&127) u32 into bucket-grouped order ----
__global__ __launch_bounds__(256) void cscatter_kernel(
    const int* __restrict__ src, const int* __restrict__ dst,
    const unsigned* __restrict__ counts, const unsigned* __restrict__ totals,
    unsigned* __restrict__ pairs, int E, int NBUCK) {
  __shared__ unsigned basec[1024];
  const int tid = threadIdx.x;
  const int bid = blockIdx.x;
  for (int i = tid; i < NBUCK; i += 256)
    basec[i] = counts[(size_t)bid * NBUCK + i] + totals[i];
  __syncthreads();
  long base = (long)bid * 2048;
#pragma unroll
  for (int c = 0; c < 8; ++c) {
    long e = base + c * 256 + tid;
    if (e < E) {
      unsigned d = (unsigned)dst[e];
      unsigned pos = atomicAdd(&basec[d >> 7], 1u);
      pairs[pos] = ((unsigned)src[e] << 7) | (d & 127u);
    }
  }
}

// ---- K_E: per-bucket fine binning -> csr_src, offs, dinv ----
__global__ __launch_bounds__(256) void fine_kernel(
    const unsigned* __restrict__ pairs, const unsigned* __restrict__ totals,
    int* __restrict__ csr_src, unsigned* __restrict__ offs, float* __restrict__ dinv,
    int N, int NBUCK, int E) {
  __shared__ int lsrc[4096];
  __shared__ ushort ldst[4096];
  __shared__ unsigned hist[128], excl[128], cur[128];
  const int tid = threadIdx.x;
  const int b = blockIdx.x;
  const unsigned t0 = totals[b], t1 = totals[b + 1];
  unsigned cnt = t1 - t0;
  if (cnt > 4096u) cnt = 4096u;  // Poisson(2048): statistically impossible
  if (tid < 128) { hist[tid] = 0u; cur[tid] = 0u; }
  __syncthreads();
  for (unsigned i = tid; i < cnt; i += 256) {
    unsigned p = pairs[t0 + i];
    lsrc[i] = (int)(p >> 7);
    int nl = (int)(p & 127u);
    ldst[i] = (ushort)nl;
    atomicAdd(&hist[nl], 1u);
  }
  __syncthreads();
  if (tid < 64) {  // exclusive scan of 128 bins (one wave, 2 chunks)
    unsigned v0 = hist[tid], v1 = hist[tid + 64];
    unsigned s0 = v0, s1 = v1;
#pragma unroll
    for (int o = 1; o < 64; o <<= 1) {
      unsigned u0 = __shfl_up(s0, o, 64);
      unsigned u1 = __shfl_up(s1, o, 64);
      if (tid >= o) { s0 += u0; s1 += u1; }
    }
    unsigned tot0 = __shfl(s0, 63, 64);
    excl[tid] = s0 - v0;
    excl[tid + 64] = tot0 + s1 - v1;
  }
  __syncthreads();
  if (tid < 128) {
    int node = (b << 7) + tid;
    if (node < N) {
      offs[node] = t0 + excl[tid];
      dinv[node] = 1.0f / fmaxf((float)hist[tid], 1.0f);
    }
  }
  if (b == 0 && tid == 255) offs[N] = (unsigned)E;
  for (unsigned i = tid; i < cnt; i += 256) {
    int nl = (int)ldst[i];
    unsigned slot = excl[nl] + atomicAdd(&cur[nl], 1u);
    csr_src[t0 + slot] = lsrc[i];
  }
}

// ================= gathers (tail-merged, proven R8) =================

#define GATHER_BODY(TABLE)                                                       \
  const int node = (blockIdx.x * 256 + threadIdx.x) >> 6;                        \
  if (node >= N) return;                                                         \
  const int lane = threadIdx.x & 63;                                             \
  const int eslot = lane >> 4;                                                   \
  const int col = lane & 15;                                                     \
  const unsigned beg = off[node], end = off[node + 1];                           \
  const ushort* fbase = (TABLE) + col * 8;                                       \
  float acc[8];                                                                  \
  _Pragma("unroll") for (int t = 0; t < 8; ++t) acc[t] = 0.f;                    \
  auto accum = [&](int4 v) {                                                     \
    unsigned w0 = (unsigned)v.x, w1 = (unsigned)v.y;                             \
    unsigned w2 = (unsigned)v.z, w3 = (unsigned)v.w;                             \
    acc[0] += __uint_as_float(w0 << 16);                                         \
    acc[1] += __uint_as_float(w0 & 0xFFFF0000u);                                 \
    acc[2] += __uint_as_float(w1 << 16);                                         \
    acc[3] += __uint_as_float(w1 & 0xFFFF0000u);                                 \
    acc[4] += __uint_as_float(w2 << 16);                                         \
    acc[5] += __uint_as_float(w2 & 0xFFFF0000u);                                 \
    acc[6] += __uint_as_float(w3 << 16);                                         \
    acc[7] += __uint_as_float(w3 & 0xFFFF0000u);                                 \
  };                                                                             \
  unsigned base = beg;                                                           \
  for (; base + 16 <= end; base += 16) {                                         \
    int s0 = csr_src[base + eslot];                                              \
    int s1 = csr_src[base + 4 + eslot];                                          \
    int s2 = csr_src[base + 8 + eslot];                                          \
    int s3 = csr_src[base + 12 + eslot];                                         \
    int4 v0 = *(const int4*)(fbase + (size_t)s0 * DIM);                          \
    int4 v1 = *(const int4*)(fbase + (size_t)s1 * DIM);                          \
    int4 v2 = *(const int4*)(fbase + (size_t)s2 * DIM);                          \
    int4 v3 = *(const int4*)(fbase + (size_t)s3 * DIM);                          \
    accum(v0); accum(v1); accum(v2); accum(v3);                                  \
  }                                                                              \
  if (base < end) {                                                              \
    unsigned e0 = base + eslot, e1 = base + 4 + eslot;                           \
    unsigned e2 = base + 8 + eslot, e3 = base + 12 + eslot;                      \
    int s0 = csr_src[e0 < end ? e0 : end - 1];                                   \
    int s1 = csr_src[e1 < end ? e1 : end - 1];                                   \
    int s2 = csr_src[e2 < end ? e2 : end - 1];                                   \
    int s3 = csr_src[e3 < end ? e3 : end - 1];                                   \
    int4 v0 = *(const int4*)(fbase + (size_t)s0 * DIM);                          \
    int4 v1 = *(const int4*)(fbase + (size_t)s1 * DIM);                          \
    int4 v2 = *(const int4*)(fbase + (size_t)s2 * DIM);                          \
    int4 v3 = *(const int4*)(fbase + (size_t)s3 * DIM);                          \
    if (e0 < end) accum(v0);                                                     \
    if (e1 < end) accum(v1);                                                     \
    if (e2 < end) accum(v2);                                                     \
    if (e3 < end) accum(v3);                                                     \
  }                                                                              \
  _Pragma("unroll") for (int t = 0; t < 8; ++t) {                                \
    acc[t] += __shfl_xor(acc[t], 32, 64);                                        \
    acc[t] += __shfl_xor(acc[t], 16, 64);                                        \
  }

// ---- gather_wave: agg(feat) * dinv -> aggH bf16 (layer 1) ----
__global__ __launch_bounds__(256) void gather_wave_kernel(
    const ushort* __restrict__ featH, const int* __restrict__ csr_src,
    const unsigned* __restrict__ off, const float* __restrict__ dinv,
    ushort* __restrict__ aggH, int N) {
  GATHER_BODY(featH)
  if (eslot == 0) {
    float di = dinv[node];
    unsigned ph[4];
#pragma unroll
    for (int t = 0; t < 4; ++t) {
      ph[t] = (unsigned)f2bf(acc[2 * t] * di) | ((unsigned)f2bf(acc[2 * t + 1] * di) << 16);
    }
    *(int4*)(aggH + (size_t)node * DIM + col * 8) =
        make_int4((int)ph[0], (int)ph[1], (int)ph[2], (int)ph[3]);
  }
}

// ---- gather2: agg(h1l) -> h2=relu(.+h1r) -> lin3 dot -> y[N][4]
// Epilogue parallelized across ALL 64 lanes: after the reduce every lane holds full
// acc; lane (col,eslot) covers dims d0=col*8+eslot*2, d0+1 (2 FMA-pairs vs 8). ----
__global__ __launch_bounds__(256) void gather2_kernel(
    const ushort* __restrict__ h1l, const int* __restrict__ csr_src,
    const unsigned* __restrict__ off, const float* __restrict__ dinv,
    const ushort* __restrict__ h1r, const float* __restrict__ W3l,
    const float* __restrict__ W3r, float* __restrict__ y, int N) {
  GATHER_BODY(h1l)
  {
    float di = dinv[node];
    // static selects, not acc[eslot*2] (runtime-indexed arrays -> scratch)
    float a0 = (eslot == 0) ? acc[0] : (eslot == 1) ? acc[2] : (eslot == 2) ? acc[4] : acc[6];
    float a1 = (eslot == 0) ? acc[1] : (eslot == 1) ? acc[3] : (eslot == 2) ? acc[5] : acc[7];
    const int d0 = col * 8 + eslot * 2;
    unsigned hv = *(const unsigned*)(h1r + (size_t)node * DIM + d0);
    float h0 = fmaxf(a0 * di + __uint_as_float(hv << 16), 0.f);
    float h1v = fmaxf(a1 * di + __uint_as_float(hv & 0xFFFF0000u), 0.f);
    float4 wl = *(const float4*)(W3l + (size_t)d0 * 2);  // rows d0, d0+1
    float4 wr = *(const float4*)(W3r + (size_t)d0 * 2);
    float y0 = h0 * wl.x + h1v * wl.z;
    float y1 = h0 * wl.y + h1v * wl.w;
    float y2 = h0 * wr.x + h1v * wr.z;
    float y3 = h0 * wr.y + h1v * wr.w;
#pragma unroll
    for (int o = 1; o < 64; o <<= 1) {
      y0 += __shfl_xor(y0, o, 64);
      y1 += __shfl_xor(y1, o, 64);
      y2 += __shfl_xor(y2, o, 64);
      y3 += __shfl_xor(y3, o, 64);
    }
    if (lane == 0) *(float4*)(y + (size_t)node * 4) = make_float4(y0, y1, y2, y3);
  }
}

// ---- sage_fused: pass1 h1 = relu(agg@W1l + x@W1r + b1) -> LDS (bf16, swizzled);
//      pass2 h1l = h1@W2l, h1r = h1@W2r + b2 (A from LDS, B direct from L2 tabs2).
//      Deletes the h1 HBM round trip (-51.2 MB) and one launch vs R8. ----
__global__ __launch_bounds__(256) void sage_fused_kernel(
    const ushort* __restrict__ aggH, const ushort* __restrict__ xH,
    const ushort* __restrict__ WlH, const ushort* __restrict__ WrH,
    const float* __restrict__ b1, const ushort* __restrict__ tabs2,
    const float* __restrict__ b2,
    ushort* __restrict__ h1l, ushort* __restrict__ h1r, int N) {
  __shared__ ushort L[2 * 128 * 64];  // 32 KB: As|Bs staging; pass2: H1 k-lo|k-hi halves
  ushort* As = L;
  ushort* Bs = L + 8192;

  const int tid = threadIdx.x;
  const int bm = blockIdx.x * 128;
  const int wave = tid >> 6;
  const int lane = tid & 63;
  const int l15 = lane & 15;
  const int quad = lane >> 4;
  const int wm = wave >> 1;
  const int wn = wave & 1;

  // ---- pass 1: h1 tile into acc ----
  f32x4 acc[4][4];
#pragma unroll
  for (int i = 0; i < 4; ++i)
#pragma unroll
    for (int j = 0; j < 4; ++j) acc[i][j] = (f32x4){0.f, 0.f, 0.f, 0.f};

  for (int g = 0; g < 4; ++g) {
    const ushort* Ap = (g < 2) ? aggH : xH;
    const ushort* Wp = (g < 2) ? WlH : WrH;
    const int kt = (g & 1) << 6;
    __syncthreads();
#pragma unroll
    for (int c = 0; c < 4; ++c) {
      int flat = c * 256 + tid;
      int row = flat >> 3;
      int kg = flat & 7;
      int swz = (kg ^ (row & 7)) << 3;
      int grow = bm + row;
      if (grow >= N) grow = N - 1;
      *(int4*)(&As[row * 64 + swz]) = *(const int4*)(Ap + (size_t)grow * DIM + kt + kg * 8);
      *(int4*)(&Bs[row * 64 + swz]) = *(const int4*)(Wp + (size_t)row * DIM + kt + kg * 8);
    }
    __syncthreads();
#pragma unroll
    for (int ks = 0; ks < 2; ++ks) {
      bf16x8 af[4], bfr[4];
      int kg = (ks << 2) + quad;
#pragma unroll
      for (int i = 0; i < 4; ++i) {
        int ar = (wm << 6) + (i << 4) + l15;
        af[i] = *(const bf16x8*)(&As[ar * 64 + ((kg ^ (ar & 7)) << 3)]);
        int br = (wn << 6) + (i << 4) + l15;
        bfr[i] = *(const bf16x8*)(&Bs[br * 64 + ((kg ^ (br & 7)) << 3)]);
      }
#pragma unroll
      for (int i = 0; i < 4; ++i)
#pragma unroll
        for (int j = 0; j < 4; ++j)
          acc[i][j] = __builtin_amdgcn_mfma_f32_16x16x32_bf16(af[i], bfr[j], acc[i][j], 0, 0, 0);
    }
  }

  float bv1[4];
#pragma unroll
  for (int j = 0; j < 4; ++j) bv1[j] = b1[(wn << 6) + (j << 4) + l15];

  // ---- h1 (bf16) into LDS with the MFMA fragment swizzle; k-halves in As / Bs ----
  __syncthreads();
#pragma unroll
  for (int i = 0; i < 4; ++i)
#pragma unroll
    for (int j = 0; j < 4; ++j)
#pragma unroll
      for (int r = 0; r < 4; ++r) {
        int row = (wm << 6) + (i << 4) + (quad << 2) + r;
        int colc = (wn << 6) + (j << 4) + l15;
        ushort* Hbuf = (colc & 64) ? Bs : As;
        int kin = colc & 63;
        Hbuf[row * 64 + ((((kin >> 3) ^ (row & 7))) << 3) + (kin & 7)] =
            f2bf(fmaxf(acc[i][j][r] + bv1[j], 0.f));
      }
  __syncthreads();

  // ---- pass 2: dual GEMM vs W2l/W2r; A-frags from LDS H1, B-frags from global tabs2 ----
  f32x4 accl[4][4], accr[4][4];
#pragma unroll
  for (int i = 0; i < 4; ++i)
#pragma unroll
    for (int j = 0; j < 4; ++j) {
      accl[i][j] = (f32x4){0.f, 0.f, 0.f, 0.f};
      accr[i][j] = (f32x4){0.f, 0.f, 0.f, 0.f};
    }

#pragma unroll
  for (int g2 = 0; g2 < 2; ++g2) {
    const int kt = g2 << 6;
    const ushort* Hbuf = g2 ? Bs : As;
#pragma unroll
    for (int ks = 0; ks < 2; ++ks) {
      int kg = (ks << 2) + quad;
      bf16x8 af[4];
#pragma unroll
      for (int i = 0; i < 4; ++i) {
        int ar = (wm << 6) + (i << 4) + l15;
        af[i] = *(const bf16x8*)(&Hbuf[ar * 64 + ((kg ^ (ar & 7)) << 3)]);
      }
#pragma unroll
      for (int j = 0; j < 4; ++j) {
        int nr = (wn << 6) + (j << 4) + l15;
        bf16x8 bl = *(const bf16x8*)(tabs2 + (size_t)nr * DIM + kt + kg * 8);
        bf16x8 br = *(const bf16x8*)(tabs2 + 16384 + (size_t)nr * DIM + kt + kg * 8);
#pragma unroll
        for (int i = 0; i < 4; ++i) {
          accl[i][j] = __builtin_amdgcn_mfma_f32_16x16x32_bf16(af[i], bl, accl[i][j], 0, 0, 0);
          accr[i][j] = __builtin_amdgcn_mfma_f32_16x16x32_bf16(af[i], br, accr[i][j], 0, 0, 0);
        }
      }
    }
  }

  float bv2[4];
#pragma unroll
  for (int j = 0; j < 4; ++j) bv2[j] = b2[(wn << 6) + (j << 4) + l15];

  // ---- epilogue: restage each mat through L (32 KB linear) -> coalesced int4 writes ----
#pragma unroll
  for (int m = 0; m < 2; ++m) {
    __syncthreads();
#pragma unroll
    for (int i = 0; i < 4; ++i)
#pragma unroll
      for (int j = 0; j < 4; ++j)
#pragma unroll
        for (int r = 0; r < 4; ++r) {
          int row = (wm << 6) + (i << 4) + (quad << 2) + r;
          int colc = (wn << 6) + (j << 4) + l15;
          float v = m ? (accr[i][j][r] + bv2[j]) : accl[i][j][r];
          L[row * 128 + colc] = f2bf(v);
        }
    __syncthreads();
    ushort* out = m ? h1r : h1l;
#pragma unroll
    for (int c = 0; c < 8; ++c) {
      int flat = c * 256 + tid;  // int4 id 0..2047
      int row = flat >> 4;
      int grow = bm + row;
      if (grow < N)
        *(int4*)(out + (size_t)grow * DIM + (flat & 15) * 8) = *(const int4*)(&L[flat * 8]);
    }
  }
}

// ---- layer 3: 2-dim CSR gather + bias + relu + log_softmax ----
__global__ __launch_bounds__(256) void final3_kernel(const float* __restrict__ y,
                                                     const int* __restrict__ csr_src,
                                                     const unsigned* __restrict__ off,
                                                     const float* __restrict__ dinv,
                                                     const float* __restrict__ b3,
                                                     float* __restrict__ out, int N) {
  int n = blockIdx.x * 256 + threadIdx.x;
  if (n >= N) return;
  unsigned beg = off[n], end = off[n + 1];
  float s0 = 0.f, s1 = 0.f;
  for (unsigned e = beg; e < end; ++e) {
    int s = csr_src[e];
    float2 v = *reinterpret_cast<const float2*>(&y[(size_t)s * 4]);
    s0 += v.x; s1 += v.y;
  }
  float di = dinv[n];
  float o0 = fmaxf(s0 * di + y[(size_t)n * 4 + 2] + b3[0], 0.f);
  float o1 = fmaxf(s1 * di + y[(size_t)n * 4 + 3] + b3[1], 0.f);
  float m = fmaxf(o0, o1);
  float l = m + logf(expf(o0 - m) + expf(o1 - m));
  out[n * 2 + 0] = o0 - l;
  out[n * 2 + 1] = o1 - l;
}

extern "C" void kernel_launch(void* const* d_in, const int* in_sizes, int n_in,
                              void* d_out, int out_size, void* d_ws, size_t ws_size,
                              hipStream_t stream) {
  const float* x   = (const float*)d_in[0];
  const int*   ei  = (const int*)d_in[1];
  const float* W1l = (const float*)d_in[2];
  const float* W1r = (const float*)d_in[3];
  const float* b1  = (const float*)d_in[4];
  const float* W2l = (const float*)d_in[5];
  const float* W2r = (const float*)d_in[6];
  const float* b2  = (const float*)d_in[7];
  const float* W3l = (const float*)d_in[8];
  const float* W3r = (const float*)d_in[9];
  const float* b3  = (const float*)d_in[10];

  const int N = in_sizes[0] / DIM;  // 100000
  const int E = in_sizes[1] / 2;    // 1600000
  const int* src = ei;
  const int* dst = ei + E;

  const int NBUCK = (N + 127) >> 7;            // 782 buckets (128 nodes each)
  const int NB    = (E + 2047) / 2048;         // 782 count/scatter blocks
  const long total_f = (long)N * DIM;
  const int CB    = (int)((total_f / 4 + 2047) / 2048);  // 1563 cast blocks

  char* ws = (char*)d_ws;
  size_t off_b = 0;
  auto alloc = [&](size_t bytes) {
    void* p = ws + off_b;
    off_b = (off_b + bytes + 255) & ~(size_t)255;
    return p;
  };
  unsigned* counts  = (unsigned*)alloc((size_t)NB * NBUCK * 4);  // 2.45 MB
  unsigned* totals  = (unsigned*)alloc((size_t)(NBUCK + 1) * 4);
  // shared_ region (25.6 MB): pairs (read last by fine) -> aggH (layer 1, each
  // sage_fused block reads only its own rows before writing the same rows as h1l).
  void*     shared_ = alloc((size_t)N * DIM * 2);
  unsigned* pairs   = (unsigned*)shared_;
  ushort*   aggH    = (ushort*)shared_;
  ushort*   h1l     = (ushort*)shared_;
  int*      csr_src = (int*)alloc((size_t)E * 4);
  unsigned* offs    = (unsigned*)alloc((size_t)(N + 1) * 4);
  float*    dinv    = (float*)alloc((size_t)N * 4);
  ushort*   xh      = (ushort*)alloc((size_t)N * DIM * 2);
  ushort*   tabs    = (ushort*)alloc((size_t)4 * 16384 * 2);
  float*    y       = (float*)alloc((size_t)N * 4 * 4);
  ushort*   h1r     = (ushort*)alloc((size_t)N * DIM * 2);
  // total ~ 88 MB

  // ---- CSR build (no global atomics, no memset) ----
  count_cast_kernel<<<NB + CB + 256, 256, 0, stream>>>(
      dst, counts, E, NB, NBUCK, x, xh, total_f, W1l, W1r, W2l, W2r, tabs, CB);
  colscan_kernel<<<(NBUCK + 3) / 4, 256, 0, stream>>>(counts, totals, NB, NBUCK);
  totscan_kernel<<<1, 256, 0, stream>>>(totals, NBUCK, E);
  cscatter_kernel<<<NB, 256, 0, stream>>>(src, dst, counts, totals, pairs, E, NBUCK);
  fine_kernel<<<NBUCK, 256, 0, stream>>>(pairs, totals, csr_src, offs, dinv, N, NBUCK, E);

  const ushort* W1lH = tabs;
  const ushort* W1rH = tabs + 16384;
  const ushort* tabs2 = tabs + 32768;  // W2l | W2r
  const int G = (N + 127) / 128;
  const int gather_grid = (N + 3) / 4;  // one wave per node

  // ---- layer 1 aggregate ----
  gather_wave_kernel<<<gather_grid, 256, 0, stream>>>(xh, csr_src, offs, dinv, aggH, N);
  // ---- layer 1 epilogue + layer 2 dual GEMM, fused (h1 never touches HBM) ----
  sage_fused_kernel<<<G, 256, 0, stream>>>(aggH, xh, W1lH, W1rH, b1, tabs2, b2, h1l, h1r, N);
  // ---- layer 2 epilogue + lin3: h2 = relu(mean_agg(h1l) + h1r); y = h2@[W3l|W3r] ----
  gather2_kernel<<<gather_grid, 256, 0, stream>>>(h1l, csr_src, offs, dinv, h1r, W3l, W3r, y, N);
  // ---- layer 3 ----
  final3_kernel<<<(N + 255) / 256, 256, 0, stream>>>(y, csr_src, offs, dinv, b3, (float*)d_out, N);
}

// Round 10
// 344.960 us; speedup vs baseline: 1.0689x; 1.0689x over previous
//
#include <hip/hip_runtime.h>
#include <math.h>

#define DIM 128

typedef __attribute__((ext_vector_type(8))) short bf16x8;
typedef __attribute__((ext_vector_type(4))) float f32x4;

__device__ __forceinline__ ushort f2bf(float f) {  // RTNE
  unsigned u = __float_as_uint(f);
  return (ushort)((u + 0x7FFFu + ((u >> 16) & 1u)) >> 16);
}
__device__ __forceinline__ float bf2f(ushort h) {
  return __uint_as_float(((unsigned)h) << 16);
}

// ================= CSR build via bucketed counting sort (NO global atomics) =================
// bucket = dst >> 7 (128 nodes/bucket); unstable binning (aggregation order-free).

// ---- K_A: per-block bucket histogram || x->bf16 cast || W1/W2 wsplit ----
__global__ __launch_bounds__(256) void count_cast_kernel(
    const int* __restrict__ dst, unsigned* __restrict__ counts, int E, int NB, int NBUCK,
    const float* __restrict__ x, ushort* __restrict__ xh, long total_f,
    const float* __restrict__ W1l, const float* __restrict__ W1r,
    const float* __restrict__ W2l, const float* __restrict__ W2r,
    ushort* __restrict__ tabs, int CB) {
  __shared__ unsigned hist[1024];
  const int tid = threadIdx.x;
  int bid = blockIdx.x;
  if (bid < NB) {  // count role: 2048 edges per block
    for (int i = tid; i < NBUCK; i += 256) hist[i] = 0u;
    __syncthreads();
    long base = (long)bid * 2048;
#pragma unroll
    for (int c = 0; c < 8; ++c) {
      long e = base + c * 256 + tid;
      if (e < E) atomicAdd(&hist[((unsigned)dst[e]) >> 7], 1u);
    }
    __syncthreads();
    for (int i = tid; i < NBUCK; i += 256)
      counts[(size_t)bid * NBUCK + i] = hist[i];
    return;
  }
  int aid = bid - NB;
  if (aid < CB) {  // cast role: 2048 float4 per block
    long i = ((long)aid * 2048 + tid) * 4;
    for (int c = 0; c < 8; ++c, i += 1024) {
      if (i >= total_f) break;
      float4 v = *(const float4*)(x + i);
      uint2 Hh;
      Hh.x = (unsigned)f2bf(v.x) | ((unsigned)f2bf(v.y) << 16);
      Hh.y = (unsigned)f2bf(v.z) | ((unsigned)f2bf(v.w) << 16);
      *(uint2*)(xh + i) = Hh;
    }
    return;
  }
  int aid2 = aid - CB;  // wsplit role: 256 blocks, 4 mats transposed+cast
  if (aid2 < 256) {
    int m = aid2 >> 6;
    const float* W = (m == 0) ? W1l : (m == 1) ? W1r : (m == 2) ? W2l : W2r;
    ushort* Ht = tabs + (size_t)m * 16384;
    int idx = (aid2 & 63) * 256 + tid;
    int k = idx >> 7, n = idx & 127;
    Ht[n * DIM + k] = f2bf(W[idx]);
  }
}

// ---- K_B: per-bucket column scan of counts[block][bucket] (one wave per bucket) ----
__global__ __launch_bounds__(256) void colscan_kernel(unsigned* __restrict__ counts,
                                                      unsigned* __restrict__ totals,
                                                      int NB, int NBUCK) {
  int wid = (blockIdx.x << 2) + (threadIdx.x >> 6);
  int lane = threadIdx.x & 63;
  if (wid >= NBUCK) return;
  unsigned carry = 0u;
  for (int k0 = 0; k0 < NB; k0 += 64) {
    int k = k0 + lane;
    unsigned v = (k < NB) ? counts[(size_t)k * NBUCK + wid] : 0u;
    unsigned s = v;
#pragma unroll
    for (int o = 1; o < 64; o <<= 1) {
      unsigned t = __shfl_up(s, o, 64);
      if (lane >= o) s += t;
    }
    if (k < NB) counts[(size_t)k * NBUCK + wid] = carry + s - v;  // exclusive
    carry += __shfl(s, 63, 64);
  }
  if (lane == 0) totals[wid] = carry;
}

// ---- K_C: scan bucket totals -> bucket bases; totals[NBUCK] = E ----
__global__ __launch_bounds__(256) void totscan_kernel(unsigned* __restrict__ totals,
                                                      int NBUCK, int E) {
  __shared__ unsigned s[256];
  __shared__ unsigned carry;
  if (threadIdx.x == 0) carry = 0u;
  __syncthreads();
  for (int base = 0; base < NBUCK; base += 256) {
    int i = base + threadIdx.x;
    unsigned v = (i < NBUCK) ? totals[i] : 0u;
    s[threadIdx.x] = v;
    __syncthreads();
#pragma unroll
    for (int d = 1; d < 256; d <<= 1) {
      unsigned t = (threadIdx.x >= d) ? s[threadIdx.x - d] : 0u;
      __syncthreads();
      s[threadIdx.x] += t;
      __syncthreads();
    }
    if (i < NBUCK) totals[i] = carry + s[threadIdx.x] - v;
    __syncthreads();
    if (threadIdx.x == 0) carry += s[255];
    __syncthreads();
  }
  if (threadIdx.x == 0) totals[NBUCK] = (unsigned)E;
}

// ---- K_D: scatter PACKED (src<<7 | dst&127) u32 into bucket-grouped order ----
__global__ __launch_bounds__(256) void cscatter_kernel(
    const int* __restrict__ src, const int* __restrict__ dst,
    const unsigned* __restrict__ counts, const unsigned* __restrict__ totals,
    unsigned* __restrict__ pairs, int E, int NBUCK) {
  __shared__ unsigned basec[1024];
  const int tid = threadIdx.x;
  const int bid = blockIdx.x;
  for (int i = tid; i < NBUCK; i += 256)
    basec[i] = counts[(size_t)bid * NBUCK + i] + totals[i];
  __syncthreads();
  long base = (long)bid * 2048;
#pragma unroll
  for (int c = 0; c < 8; ++c) {
    long e = base + c * 256 + tid;
    if (e < E) {
      unsigned d = (unsigned)dst[e];
      unsigned pos = atomicAdd(&basec[d >> 7], 1u);
      pairs[pos] = ((unsigned)src[e] << 7) | (d & 127u);
    }
  }
}

// ---- K_E: per-bucket fine binning -> csr_src, offs, dinv ----
__global__ __launch_bounds__(256) void fine_kernel(
    const unsigned* __restrict__ pairs, const unsigned* __restrict__ totals,
    int* __restrict__ csr_src, unsigned* __restrict__ offs, float* __restrict__ dinv,
    int N, int NBUCK, int E) {
  __shared__ int lsrc[4096];
  __shared__ ushort ldst[4096];
  __shared__ unsigned hist[128], excl[128], cur[128];
  const int tid = threadIdx.x;
  const int b = blockIdx.x;
  const unsigned t0 = totals[b], t1 = totals[b + 1];
  unsigned cnt = t1 - t0;
  if (cnt > 4096u) cnt = 4096u;  // Poisson(2048): statistically impossible
  if (tid < 128) { hist[tid] = 0u; cur[tid] = 0u; }
  __syncthreads();
  for (unsigned i = tid; i < cnt; i += 256) {
    unsigned p = pairs[t0 + i];
    lsrc[i] = (int)(p >> 7);
    int nl = (int)(p & 127u);
    ldst[i] = (ushort)nl;
    atomicAdd(&hist[nl], 1u);
  }
  __syncthreads();
  if (tid < 64) {  // exclusive scan of 128 bins (one wave, 2 chunks)
    unsigned v0 = hist[tid], v1 = hist[tid + 64];
    unsigned s0 = v0, s1 = v1;
#pragma unroll
    for (int o = 1; o < 64; o <<= 1) {
      unsigned u0 = __shfl_up(s0, o, 64);
      unsigned u1 = __shfl_up(s1, o, 64);
      if (tid >= o) { s0 += u0; s1 += u1; }
    }
    unsigned tot0 = __shfl(s0, 63, 64);
    excl[tid] = s0 - v0;
    excl[tid + 64] = tot0 + s1 - v1;
  }
  __syncthreads();
  if (tid < 128) {
    int node = (b << 7) + tid;
    if (node < N) {
      offs[node] = t0 + excl[tid];
      dinv[node] = 1.0f / fmaxf((float)hist[tid], 1.0f);
    }
  }
  if (b == 0 && tid == 255) offs[N] = (unsigned)E;
  for (unsigned i = tid; i < cnt; i += 256) {
    int nl = (int)ldst[i];
    unsigned slot = excl[nl] + atomicAdd(&cur[nl], 1u);
    csr_src[t0 + slot] = lsrc[i];
  }
}

// ================= gathers (tail-merged, proven R8) =================

#define GATHER_BODY(TABLE)                                                       \
  const int node = (blockIdx.x * 256 + threadIdx.x) >> 6;                        \
  if (node >= N) return;                                                         \
  const int lane = threadIdx.x & 63;                                             \
  const int eslot = lane >> 4;                                                   \
  const int col = lane & 15;                                                     \
  const unsigned beg = off[node], end = off[node + 1];                           \
  const ushort* fbase = (TABLE) + col * 8;                                       \
  float acc[8];                                                                  \
  _Pragma("unroll") for (int t = 0; t < 8; ++t) acc[t] = 0.f;                    \
  auto accum = [&](int4 v) {                                                     \
    unsigned w0 = (unsigned)v.x, w1 = (unsigned)v.y;                             \
    unsigned w2 = (unsigned)v.z, w3 = (unsigned)v.w;                             \
    acc[0] += __uint_as_float(w0 << 16);                                         \
    acc[1] += __uint_as_float(w0 & 0xFFFF0000u);                                 \
    acc[2] += __uint_as_float(w1 << 16);                                         \
    acc[3] += __uint_as_float(w1 & 0xFFFF0000u);                                 \
    acc[4] += __uint_as_float(w2 << 16);                                         \
    acc[5] += __uint_as_float(w2 & 0xFFFF0000u);                                 \
    acc[6] += __uint_as_float(w3 << 16);                                         \
    acc[7] += __uint_as_float(w3 & 0xFFFF0000u);                                 \
  };                                                                             \
  unsigned base = beg;                                                           \
  for (; base + 16 <= end; base += 16) {                                         \
    int s0 = csr_src[base + eslot];                                              \
    int s1 = csr_src[base + 4 + eslot];                                          \
    int s2 = csr_src[base + 8 + eslot];                                          \
    int s3 = csr_src[base + 12 + eslot];                                         \
    int4 v0 = *(const int4*)(fbase + (size_t)s0 * DIM);                          \
    int4 v1 = *(const int4*)(fbase + (size_t)s1 * DIM);                          \
    int4 v2 = *(const int4*)(fbase + (size_t)s2 * DIM);                          \
    int4 v3 = *(const int4*)(fbase + (size_t)s3 * DIM);                          \
    accum(v0); accum(v1); accum(v2); accum(v3);                                  \
  }                                                                              \
  if (base < end) {                                                              \
    unsigned e0 = base + eslot, e1 = base + 4 + eslot;                           \
    unsigned e2 = base + 8 + eslot, e3 = base + 12 + eslot;                      \
    int s0 = csr_src[e0 < end ? e0 : end - 1];                                   \
    int s1 = csr_src[e1 < end ? e1 : end - 1];                                   \
    int s2 = csr_src[e2 < end ? e2 : end - 1];                                   \
    int s3 = csr_src[e3 < end ? e3 : end - 1];                                   \
    int4 v0 = *(const int4*)(fbase + (size_t)s0 * DIM);                          \
    int4 v1 = *(const int4*)(fbase + (size_t)s1 * DIM);                          \
    int4 v2 = *(const int4*)(fbase + (size_t)s2 * DIM);                          \
    int4 v3 = *(const int4*)(fbase + (size_t)s3 * DIM);                          \
    if (e0 < end) accum(v0);                                                     \
    if (e1 < end) accum(v1);                                                     \
    if (e2 < end) accum(v2);                                                     \
    if (e3 < end) accum(v3);                                                     \
  }                                                                              \
  _Pragma("unroll") for (int t = 0; t < 8; ++t) {                                \
    acc[t] += __shfl_xor(acc[t], 32, 64);                                        \
    acc[t] += __shfl_xor(acc[t], 16, 64);                                        \
  }

// ---- gather_wave: agg(feat) * dinv -> aggH bf16 (layer 1) ----
__global__ __launch_bounds__(256) void gather_wave_kernel(
    const ushort* __restrict__ featH, const int* __restrict__ csr_src,
    const unsigned* __restrict__ off, const float* __restrict__ dinv,
    ushort* __restrict__ aggH, int N) {
  GATHER_BODY(featH)
  if (eslot == 0) {
    float di = dinv[node];
    unsigned ph[4];
#pragma unroll
    for (int t = 0; t < 4; ++t) {
      ph[t] = (unsigned)f2bf(acc[2 * t] * di) | ((unsigned)f2bf(acc[2 * t + 1] * di) << 16);
    }
    *(int4*)(aggH + (size_t)node * DIM + col * 8) =
        make_int4((int)ph[0], (int)ph[1], (int)ph[2], (int)ph[3]);
  }
}

// ---- gather2: agg(h1l) -> h2=relu(.+h1r) -> lin3 dot -> y[N][4]
// Epilogue parallelized across ALL 64 lanes (R9-proven: 79.4 -> 64.4 us):
// lane (col,eslot) covers dims d0=col*8+eslot*2, d0+1. ----
__global__ __launch_bounds__(256) void gather2_kernel(
    const ushort* __restrict__ h1l, const int* __restrict__ csr_src,
    const unsigned* __restrict__ off, const float* __restrict__ dinv,
    const ushort* __restrict__ h1r, const float* __restrict__ W3l,
    const float* __restrict__ W3r, float* __restrict__ y, int N) {
  GATHER_BODY(h1l)
  {
    float di = dinv[node];
    // static selects, not acc[eslot*2] (runtime-indexed arrays -> scratch)
    float a0 = (eslot == 0) ? acc[0] : (eslot == 1) ? acc[2] : (eslot == 2) ? acc[4] : acc[6];
    float a1 = (eslot == 0) ? acc[1] : (eslot == 1) ? acc[3] : (eslot == 2) ? acc[5] : acc[7];
    const int d0 = col * 8 + eslot * 2;
    unsigned hv = *(const unsigned*)(h1r + (size_t)node * DIM + d0);
    float h0 = fmaxf(a0 * di + __uint_as_float(hv << 16), 0.f);
    float h1v = fmaxf(a1 * di + __uint_as_float(hv & 0xFFFF0000u), 0.f);
    float4 wl = *(const float4*)(W3l + (size_t)d0 * 2);  // rows d0, d0+1
    float4 wr = *(const float4*)(W3r + (size_t)d0 * 2);
    float y0 = h0 * wl.x + h1v * wl.z;
    float y1 = h0 * wl.y + h1v * wl.w;
    float y2 = h0 * wr.x + h1v * wr.z;
    float y3 = h0 * wr.y + h1v * wr.w;
#pragma unroll
    for (int o = 1; o < 64; o <<= 1) {
      y0 += __shfl_xor(y0, o, 64);
      y1 += __shfl_xor(y1, o, 64);
      y2 += __shfl_xor(y2, o, 64);
      y3 += __shfl_xor(y3, o, 64);
    }
    if (lane == 0) *(float4*)(y + (size_t)node * 4) = make_float4(y0, y1, y2, y3);
  }
}

// ---- MFMA SAGE layer 1: h1 = relu(agg@W1l + x@W1r + b1), in-place over xh (R8-proven) ----
__global__ __launch_bounds__(256) void sage_mfma_kernel(
    const ushort* __restrict__ aggH, const ushort* xH,
    const ushort* __restrict__ WlH, const ushort* __restrict__ WrH,
    const float* __restrict__ bias, ushort* __restrict__ outH, int N) {
  __shared__ ushort As[128 * 64];  // 16 KB
  __shared__ ushort Bs[128 * 64];  // 16 KB

  const int tid = threadIdx.x;
  const int bm = blockIdx.x * 128;
  const int wave = tid >> 6;
  const int lane = tid & 63;
  const int l15 = lane & 15;
  const int quad = lane >> 4;
  const int wm = wave >> 1;
  const int wn = wave & 1;

  f32x4 acc[4][4];
#pragma unroll
  for (int i = 0; i < 4; ++i)
#pragma unroll
    for (int j = 0; j < 4; ++j) acc[i][j] = (f32x4){0.f, 0.f, 0.f, 0.f};

  for (int g = 0; g < 4; ++g) {
    const ushort* Ap = (g < 2) ? aggH : xH;
    const ushort* Wp = (g < 2) ? WlH : WrH;
    const int kt = (g & 1) << 6;
    __syncthreads();
#pragma unroll
    for (int c = 0; c < 4; ++c) {
      int flat = c * 256 + tid;
      int row = flat >> 3;
      int kg = flat & 7;
      int swz = (kg ^ (row & 7)) << 3;
      int grow = bm + row;
      if (grow >= N) grow = N - 1;
      *(int4*)(&As[row * 64 + swz]) = *(const int4*)(Ap + (size_t)grow * DIM + kt + kg * 8);
      *(int4*)(&Bs[row * 64 + swz]) = *(const int4*)(Wp + (size_t)row * DIM + kt + kg * 8);
    }
    __syncthreads();
#pragma unroll
    for (int ks = 0; ks < 2; ++ks) {
      bf16x8 af[4], bfr[4];
      int kg = (ks << 2) + quad;
#pragma unroll
      for (int i = 0; i < 4; ++i) {
        int ar = (wm << 6) + (i << 4) + l15;
        af[i] = *(const bf16x8*)(&As[ar * 64 + ((kg ^ (ar & 7)) << 3)]);
        int br = (wn << 6) + (i << 4) + l15;
        bfr[i] = *(const bf16x8*)(&Bs[br * 64 + ((kg ^ (br & 7)) << 3)]);
      }
#pragma unroll
      for (int i = 0; i < 4; ++i)
#pragma unroll
        for (int j = 0; j < 4; ++j)
          acc[i][j] = __builtin_amdgcn_mfma_f32_16x16x32_bf16(af[i], bfr[j], acc[i][j], 0, 0, 0);
    }
  }

  float bv[4];
#pragma unroll
  for (int j = 0; j < 4; ++j) bv[j] = bias[(wn << 6) + (j << 4) + l15];

  // epilogue: restage relu(acc+b) through LDS -> coalesced int4 writes
  __syncthreads();
#pragma unroll
  for (int i = 0; i < 4; ++i)
#pragma unroll
    for (int j = 0; j < 4; ++j)
#pragma unroll
      for (int r = 0; r < 4; ++r) {
        int row = (wm << 6) + (i << 4) + (quad << 2) + r;
        int colc = (wn << 6) + (j << 4) + l15;
        ((ushort*)As)[((row & 63) << 7) + colc + ((row >> 6) << 13)] =
            f2bf(fmaxf(acc[i][j][r] + bv[j], 0.f));
      }
  __syncthreads();
#pragma unroll
  for (int c = 0; c < 8; ++c) {
    int flat = c * 256 + tid;  // int4 id 0..2047 over 128x128
    int row = flat >> 4;
    int grow = bm + row;
    if (grow < N)
      *(int4*)(outH + (size_t)grow * DIM + (flat & 15) * 8) =
          *(const int4*)((const ushort*)As + flat * 8);
  }
}

// ---- gemm2_dual: h1l = h1@W2l, h1r = h1@W2r + b2 -- h1 read ONCE, LDS-staged writes (R8-proven) ----
__global__ __launch_bounds__(256) void gemm2_dual_kernel(
    const ushort* __restrict__ h1, const ushort* __restrict__ tabs2,
    const float* __restrict__ b2, ushort* __restrict__ h1l, ushort* __restrict__ h1r, int N) {
  __shared__ ushort L[3 * 128 * 64];  // 48 KB: As | Bs0 (W2l) | Bs1 (W2r)
  ushort* As = L;
  ushort* Bs0 = L + 8192;
  ushort* Bs1 = L + 16384;
  const int tid = threadIdx.x;
  const int bm = blockIdx.x * 128;
  const int wave = tid >> 6;
  const int lane = tid & 63;
  const int l15 = lane & 15;
  const int quad = lane >> 4;
  const int wm = wave >> 1;
  const int wn = wave & 1;

  f32x4 accl[4][4], accr[4][4];
#pragma unroll
  for (int i = 0; i < 4; ++i)
#pragma unroll
    for (int j = 0; j < 4; ++j) {
      accl[i][j] = (f32x4){0.f, 0.f, 0.f, 0.f};
      accr[i][j] = (f32x4){0.f, 0.f, 0.f, 0.f};
    }

  for (int g = 0; g < 2; ++g) {
    const int kt = g << 6;
    __syncthreads();
#pragma unroll
    for (int c = 0; c < 4; ++c) {
      int flat = c * 256 + tid;
      int row = flat >> 3;
      int kg = flat & 7;
      int swz = (kg ^ (row & 7)) << 3;
      int grow = bm + row;
      if (grow >= N) grow = N - 1;
      *(int4*)(&As[row * 64 + swz]) = *(const int4*)(h1 + (size_t)grow * DIM + kt + kg * 8);
      *(int4*)(&Bs0[row * 64 + swz]) = *(const int4*)(tabs2 + (size_t)row * DIM + kt + kg * 8);
      *(int4*)(&Bs1[row * 64 + swz]) =
          *(const int4*)(tabs2 + 16384 + (size_t)row * DIM + kt + kg * 8);
    }
    __syncthreads();
#pragma unroll
    for (int ks = 0; ks < 2; ++ks) {
      bf16x8 af[4], bl[4], br[4];
      int kg = (ks << 2) + quad;
#pragma unroll
      for (int i = 0; i < 4; ++i) {
        int ar = (wm << 6) + (i << 4) + l15;
        af[i] = *(const bf16x8*)(&As[ar * 64 + ((kg ^ (ar & 7)) << 3)]);
        int nr = (wn << 6) + (i << 4) + l15;
        bl[i] = *(const bf16x8*)(&Bs0[nr * 64 + ((kg ^ (nr & 7)) << 3)]);
        br[i] = *(const bf16x8*)(&Bs1[nr * 64 + ((kg ^ (nr & 7)) << 3)]);
      }
#pragma unroll
      for (int i = 0; i < 4; ++i)
#pragma unroll
        for (int j = 0; j < 4; ++j) {
          accl[i][j] = __builtin_amdgcn_mfma_f32_16x16x32_bf16(af[i], bl[j], accl[i][j], 0, 0, 0);
          accr[i][j] = __builtin_amdgcn_mfma_f32_16x16x32_bf16(af[i], br[j], accr[i][j], 0, 0, 0);
        }
    }
  }

  float bv[4];
#pragma unroll
  for (int j = 0; j < 4; ++j) bv[j] = b2[(wn << 6) + (j << 4) + l15];

  // epilogue: restage each mat through L[0..16383] (32 KB) -> coalesced int4 writes
#pragma unroll
  for (int m = 0; m < 2; ++m) {
    __syncthreads();
#pragma unroll
    for (int i = 0; i < 4; ++i)
#pragma unroll
      for (int j = 0; j < 4; ++j)
#pragma unroll
        for (int r = 0; r < 4; ++r) {
          int row = (wm << 6) + (i << 4) + (quad << 2) + r;
          int colc = (wn << 6) + (j << 4) + l15;
          float v = m ? (accr[i][j][r] + bv[j]) : accl[i][j][r];
          L[row * 128 + colc] = f2bf(v);
        }
    __syncthreads();
    ushort* out = m ? h1r : h1l;
#pragma unroll
    for (int c = 0; c < 8; ++c) {
      int flat = c * 256 + tid;  // int4 id 0..2047
      int row = flat >> 4;
      int grow = bm + row;
      if (grow < N)
        *(int4*)(out + (size_t)grow * DIM + (flat & 15) * 8) = *(const int4*)(&L[flat * 8]);
    }
  }
}

// ---- layer 3: 2-dim CSR gather + bias + relu + log_softmax ----
__global__ __launch_bounds__(256) void final3_kernel(const float* __restrict__ y,
                                                     const int* __restrict__ csr_src,
                                                     const unsigned* __restrict__ off,
                                                     const float* __restrict__ dinv,
                                                     const float* __restrict__ b3,
                                                     float* __restrict__ out, int N) {
  int n = blockIdx.x * 256 + threadIdx.x;
  if (n >= N) return;
  unsigned beg = off[n], end = off[n + 1];
  float s0 = 0.f, s1 = 0.f;
  for (unsigned e = beg; e < end; ++e) {
    int s = csr_src[e];
    float2 v = *reinterpret_cast<const float2*>(&y[(size_t)s * 4]);
    s0 += v.x; s1 += v.y;
  }
  float di = dinv[n];
  float o0 = fmaxf(s0 * di + y[(size_t)n * 4 + 2] + b3[0], 0.f);
  float o1 = fmaxf(s1 * di + y[(size_t)n * 4 + 3] + b3[1], 0.f);
  float m = fmaxf(o0, o1);
  float l = m + logf(expf(o0 - m) + expf(o1 - m));
  out[n * 2 + 0] = o0 - l;
  out[n * 2 + 1] = o1 - l;
}

extern "C" void kernel_launch(void* const* d_in, const int* in_sizes, int n_in,
                              void* d_out, int out_size, void* d_ws, size_t ws_size,
                              hipStream_t stream) {
  const float* x   = (const float*)d_in[0];
  const int*   ei  = (const int*)d_in[1];
  const float* W1l = (const float*)d_in[2];
  const float* W1r = (const float*)d_in[3];
  const float* b1  = (const float*)d_in[4];
  const float* W2l = (const float*)d_in[5];
  const float* W2r = (const float*)d_in[6];
  const float* b2  = (const float*)d_in[7];
  const float* W3l = (const float*)d_in[8];
  const float* W3r = (const float*)d_in[9];
  const float* b3  = (const float*)d_in[10];

  const int N = in_sizes[0] / DIM;  // 100000
  const int E = in_sizes[1] / 2;    // 1600000
  const int* src = ei;
  const int* dst = ei + E;

  const int NBUCK = (N + 127) >> 7;            // 782 buckets (128 nodes each)
  const int NB    = (E + 2047) / 2048;         // 782 count/scatter blocks
  const long total_f = (long)N * DIM;
  const int CB    = (int)((total_f / 4 + 2047) / 2048);  // 1563 cast blocks

  char* ws = (char*)d_ws;
  size_t off_b = 0;
  auto alloc = [&](size_t bytes) {
    void* p = ws + off_b;
    off_b = (off_b + bytes + 255) & ~(size_t)255;
    return p;
  };
  unsigned* counts  = (unsigned*)alloc((size_t)NB * NBUCK * 4);  // 2.45 MB
  unsigned* totals  = (unsigned*)alloc((size_t)(NBUCK + 1) * 4);
  // shared_ region (25.6 MB): pairs (read last by fine) -> aggH (layer 1, read last
  // by sage_mfma) -> h1l (written by gemm2_dual strictly afterwards).
  void*     shared_ = alloc((size_t)N * DIM * 2);
  unsigned* pairs   = (unsigned*)shared_;
  ushort*   aggH    = (ushort*)shared_;
  ushort*   h1l     = (ushort*)shared_;
  int*      csr_src = (int*)alloc((size_t)E * 4);
  unsigned* offs    = (unsigned*)alloc((size_t)(N + 1) * 4);
  float*    dinv    = (float*)alloc((size_t)N * 4);
  ushort*   xh      = (ushort*)alloc((size_t)N * DIM * 2);
  ushort*   tabs    = (ushort*)alloc((size_t)4 * 16384 * 2);
  float*    y       = (float*)alloc((size_t)N * 4 * 4);
  ushort*   h1r     = (ushort*)alloc((size_t)N * DIM * 2);
  // total ~ 88 MB

  // ---- CSR build (no global atomics, no memset) ----
  count_cast_kernel<<<NB + CB + 256, 256, 0, stream>>>(
      dst, counts, E, NB, NBUCK, x, xh, total_f, W1l, W1r, W2l, W2r, tabs, CB);
  colscan_kernel<<<(NBUCK + 3) / 4, 256, 0, stream>>>(counts, totals, NB, NBUCK);
  totscan_kernel<<<1, 256, 0, stream>>>(totals, NBUCK, E);
  cscatter_kernel<<<NB, 256, 0, stream>>>(src, dst, counts, totals, pairs, E, NBUCK);
  fine_kernel<<<NBUCK, 256, 0, stream>>>(pairs, totals, csr_src, offs, dinv, N, NBUCK, E);

  const ushort* W1lH = tabs;
  const ushort* W1rH = tabs + 16384;
  const ushort* tabs2 = tabs + 32768;  // W2l | W2r
  const int G = (N + 127) / 128;
  const int gather_grid = (N + 3) / 4;  // one wave per node

  // ---- layer 1: h1 = relu(agg@W1l + x@W1r + b1), in-place over xh ----
  gather_wave_kernel<<<gather_grid, 256, 0, stream>>>(xh, csr_src, offs, dinv, aggH, N);
  sage_mfma_kernel<<<G, 256, 0, stream>>>(aggH, xh, W1lH, W1rH, b1, xh, N);
  // ---- layer 2 via linearity: h1l = h1@W2l, h1r = h1@W2r + b2 (h1 read once) ----
  gemm2_dual_kernel<<<G, 256, 0, stream>>>(xh, tabs2, b2, h1l, h1r, N);
  // ---- layer 2 epilogue + lin3: h2 = relu(mean_agg(h1l) + h1r); y = h2@[W3l|W3r] ----
  gather2_kernel<<<gather_grid, 256, 0, stream>>>(h1l, csr_src, offs, dinv, h1r, W3l, W3r, y, N);
  // ---- layer 3 ----
  final3_kernel<<<(N + 255) / 256, 256, 0, stream>>>(y, csr_src, offs, dinv, b3, (float*)d_out, N);
}

// Round 11
// 341.505 us; speedup vs baseline: 1.0797x; 1.0101x over previous
//
#include <hip/hip_runtime.h>
#include <math.h>

#define DIM 128

typedef __attribute__((ext_vector_type(8))) short bf16x8;
typedef __attribute__((ext_vector_type(4))) float f32x4;

__device__ __forceinline__ ushort f2bf(float f) {  // RTNE
  unsigned u = __float_as_uint(f);
  return (ushort)((u + 0x7FFFu + ((u >> 16) & 1u)) >> 16);
}
__device__ __forceinline__ float bf2f(ushort h) {
  return __uint_as_float(((unsigned)h) << 16);
}

// ================= CSR build via bucketed counting sort (NO global atomics) =================
// bucket = dst >> 7 (128 nodes/bucket); unstable binning (aggregation order-free).

// ---- K_A: per-block bucket histogram || W1/W2 wsplit (cast role deleted: x is cast
// inside gemm1_dual's A-stage now) ----
__global__ __launch_bounds__(256) void count_wsplit_kernel(
    const int* __restrict__ dst, unsigned* __restrict__ counts, int E, int NB, int NBUCK,
    const float* __restrict__ W1l, const float* __restrict__ W1r,
    const float* __restrict__ W2l, const float* __restrict__ W2r,
    ushort* __restrict__ tabs) {
  __shared__ unsigned hist[1024];
  const int tid = threadIdx.x;
  int bid = blockIdx.x;
  if (bid < NB) {  // count role: 2048 edges per block
    for (int i = tid; i < NBUCK; i += 256) hist[i] = 0u;
    __syncthreads();
    long base = (long)bid * 2048;
#pragma unroll
    for (int c = 0; c < 8; ++c) {
      long e = base + c * 256 + tid;
      if (e < E) atomicAdd(&hist[((unsigned)dst[e]) >> 7], 1u);
    }
    __syncthreads();
    for (int i = tid; i < NBUCK; i += 256)
      counts[(size_t)bid * NBUCK + i] = hist[i];
    return;
  }
  int aid2 = bid - NB;  // wsplit role: 256 blocks, 4 mats transposed+cast to [n][k]
  if (aid2 < 256) {
    int m = aid2 >> 6;
    const float* W = (m == 0) ? W1l : (m == 1) ? W1r : (m == 2) ? W2l : W2r;
    ushort* Ht = tabs + (size_t)m * 16384;
    int idx = (aid2 & 63) * 256 + tid;
    int k = idx >> 7, n = idx & 127;
    Ht[n * DIM + k] = f2bf(W[idx]);
  }
}

// ---- K_B: per-bucket column scan of counts[block][bucket] (one wave per bucket) ----
__global__ __launch_bounds__(256) void colscan_kernel(unsigned* __restrict__ counts,
                                                      unsigned* __restrict__ totals,
                                                      int NB, int NBUCK) {
  int wid = (blockIdx.x << 2) + (threadIdx.x >> 6);
  int lane = threadIdx.x & 63;
  if (wid >= NBUCK) return;
  unsigned carry = 0u;
  for (int k0 = 0; k0 < NB; k0 += 64) {
    int k = k0 + lane;
    unsigned v = (k < NB) ? counts[(size_t)k * NBUCK + wid] : 0u;
    unsigned s = v;
#pragma unroll
    for (int o = 1; o < 64; o <<= 1) {
      unsigned t = __shfl_up(s, o, 64);
      if (lane >= o) s += t;
    }
    if (k < NB) counts[(size_t)k * NBUCK + wid] = carry + s - v;  // exclusive
    carry += __shfl(s, 63, 64);
  }
  if (lane == 0) totals[wid] = carry;
}

// ---- K_C: scan bucket totals -> bucket bases; totals[NBUCK] = E ----
__global__ __launch_bounds__(256) void totscan_kernel(unsigned* __restrict__ totals,
                                                      int NBUCK, int E) {
  __shared__ unsigned s[256];
  __shared__ unsigned carry;
  if (threadIdx.x == 0) carry = 0u;
  __syncthreads();
  for (int base = 0; base < NBUCK; base += 256) {
    int i = base + threadIdx.x;
    unsigned v = (i < NBUCK) ? totals[i] : 0u;
    s[threadIdx.x] = v;
    __syncthreads();
#pragma unroll
    for (int d = 1; d < 256; d <<= 1) {
      unsigned t = (threadIdx.x >= d) ? s[threadIdx.x - d] : 0u;
      __syncthreads();
      s[threadIdx.x] += t;
      __syncthreads();
    }
    if (i < NBUCK) totals[i] = carry + s[threadIdx.x] - v;
    __syncthreads();
    if (threadIdx.x == 0) carry += s[255];
    __syncthreads();
  }
  if (threadIdx.x == 0) totals[NBUCK] = (unsigned)E;
}

// ---- K_D: scatter PACKED (src<<7 | dst&127) u32 into bucket-grouped order ----
__global__ __launch_bounds__(256) void cscatter_kernel(
    const int* __restrict__ src, const int* __restrict__ dst,
    const unsigned* __restrict__ counts, const unsigned* __restrict__ totals,
    unsigned* __restrict__ pairs, int E, int NBUCK) {
  __shared__ unsigned basec[1024];
  const int tid = threadIdx.x;
  const int bid = blockIdx.x;
  for (int i = tid; i < NBUCK; i += 256)
    basec[i] = counts[(size_t)bid * NBUCK + i] + totals[i];
  __syncthreads();
  long base = (long)bid * 2048;
#pragma unroll
  for (int c = 0; c < 8; ++c) {
    long e = base + c * 256 + tid;
    if (e < E) {
      unsigned d = (unsigned)dst[e];
      unsigned pos = atomicAdd(&basec[d >> 7], 1u);
      pairs[pos] = ((unsigned)src[e] << 7) | (d & 127u);
    }
  }
}

// ---- K_E: per-bucket fine binning -> csr_src, offs, dinv ----
__global__ __launch_bounds__(256) void fine_kernel(
    const unsigned* __restrict__ pairs, const unsigned* __restrict__ totals,
    int* __restrict__ csr_src, unsigned* __restrict__ offs, float* __restrict__ dinv,
    int N, int NBUCK, int E) {
  __shared__ int lsrc[4096];
  __shared__ ushort ldst[4096];
  __shared__ unsigned hist[128], excl[128], cur[128];
  const int tid = threadIdx.x;
  const int b = blockIdx.x;
  const unsigned t0 = totals[b], t1 = totals[b + 1];
  unsigned cnt = t1 - t0;
  if (cnt > 4096u) cnt = 4096u;  // Poisson(2048): statistically impossible
  if (tid < 128) { hist[tid] = 0u; cur[tid] = 0u; }
  __syncthreads();
  for (unsigned i = tid; i < cnt; i += 256) {
    unsigned p = pairs[t0 + i];
    lsrc[i] = (int)(p >> 7);
    int nl = (int)(p & 127u);
    ldst[i] = (ushort)nl;
    atomicAdd(&hist[nl], 1u);
  }
  __syncthreads();
  if (tid < 64) {  // exclusive scan of 128 bins (one wave, 2 chunks)
    unsigned v0 = hist[tid], v1 = hist[tid + 64];
    unsigned s0 = v0, s1 = v1;
#pragma unroll
    for (int o = 1; o < 64; o <<= 1) {
      unsigned u0 = __shfl_up(s0, o, 64);
      unsigned u1 = __shfl_up(s1, o, 64);
      if (tid >= o) { s0 += u0; s1 += u1; }
    }
    unsigned tot0 = __shfl(s0, 63, 64);
    excl[tid] = s0 - v0;
    excl[tid + 64] = tot0 + s1 - v1;
  }
  __syncthreads();
  if (tid < 128) {
    int node = (b << 7) + tid;
    if (node < N) {
      offs[node] = t0 + excl[tid];
      dinv[node] = 1.0f / fmaxf((float)hist[tid], 1.0f);
    }
  }
  if (b == 0 && tid == 255) offs[N] = (unsigned)E;
  for (unsigned i = tid; i < cnt; i += 256) {
    int nl = (int)ldst[i];
    unsigned slot = excl[nl] + atomicAdd(&cur[nl], 1u);
    csr_src[t0 + slot] = lsrc[i];
  }
}

// ================= gathers (tail-merged, proven R8) =================

#define GATHER_BODY(TABLE)                                                       \
  const int node = (blockIdx.x * 256 + threadIdx.x) >> 6;                        \
  if (node >= N) return;                                                         \
  const int lane = threadIdx.x & 63;                                             \
  const int eslot = lane >> 4;                                                   \
  const int col = lane & 15;                                                     \
  const unsigned beg = off[node], end = off[node + 1];                           \
  const ushort* fbase = (TABLE) + col * 8;                                       \
  float acc[8];                                                                  \
  _Pragma("unroll") for (int t = 0; t < 8; ++t) acc[t] = 0.f;                    \
  auto accum = [&](int4 v) {                                                     \
    unsigned w0 = (unsigned)v.x, w1 = (unsigned)v.y;                             \
    unsigned w2 = (unsigned)v.z, w3 = (unsigned)v.w;                             \
    acc[0] += __uint_as_float(w0 << 16);                                         \
    acc[1] += __uint_as_float(w0 & 0xFFFF0000u);                                 \
    acc[2] += __uint_as_float(w1 << 16);                                         \
    acc[3] += __uint_as_float(w1 & 0xFFFF0000u);                                 \
    acc[4] += __uint_as_float(w2 << 16);                                         \
    acc[5] += __uint_as_float(w2 & 0xFFFF0000u);                                 \
    acc[6] += __uint_as_float(w3 << 16);                                         \
    acc[7] += __uint_as_float(w3 & 0xFFFF0000u);                                 \
  };                                                                             \
  unsigned base = beg;                                                           \
  for (; base + 16 <= end; base += 16) {                                         \
    int s0 = csr_src[base + eslot];                                              \
    int s1 = csr_src[base + 4 + eslot];                                          \
    int s2 = csr_src[base + 8 + eslot];                                          \
    int s3 = csr_src[base + 12 + eslot];                                         \
    int4 v0 = *(const int4*)(fbase + (size_t)s0 * DIM);                          \
    int4 v1 = *(const int4*)(fbase + (size_t)s1 * DIM);                          \
    int4 v2 = *(const int4*)(fbase + (size_t)s2 * DIM);                          \
    int4 v3 = *(const int4*)(fbase + (size_t)s3 * DIM);                          \
    accum(v0); accum(v1); accum(v2); accum(v3);                                  \
  }                                                                              \
  if (base < end) {                                                              \
    unsigned e0 = base + eslot, e1 = base + 4 + eslot;                           \
    unsigned e2 = base + 8 + eslot, e3 = base + 12 + eslot;                      \
    int s0 = csr_src[e0 < end ? e0 : end - 1];                                   \
    int s1 = csr_src[e1 < end ? e1 : end - 1];                                   \
    int s2 = csr_src[e2 < end ? e2 : end - 1];                                   \
    int s3 = csr_src[e3 < end ? e3 : end - 1];                                   \
    int4 v0 = *(const int4*)(fbase + (size_t)s0 * DIM);                          \
    int4 v1 = *(const int4*)(fbase + (size_t)s1 * DIM);                          \
    int4 v2 = *(const int4*)(fbase + (size_t)s2 * DIM);                          \
    int4 v3 = *(const int4*)(fbase + (size_t)s3 * DIM);                          \
    if (e0 < end) accum(v0);                                                     \
    if (e1 < end) accum(v1);                                                     \
    if (e2 < end) accum(v2);                                                     \
    if (e3 < end) accum(v3);                                                     \
  }                                                                              \
  _Pragma("unroll") for (int t = 0; t < 8; ++t) {                                \
    acc[t] += __shfl_xor(acc[t], 32, 64);                                        \
    acc[t] += __shfl_xor(acc[t], 16, 64);                                        \
  }

// ---- gather1: agg(xl) -> h1 = relu(agg*dinv + xr + b1), all-lane epilogue ----
// (epilogue math proven R2; lane-parallel form proven R9's gather2)
__global__ __launch_bounds__(256) void gather1_kernel(
    const ushort* __restrict__ xl, const int* __restrict__ csr_src,
    const unsigned* __restrict__ off, const float* __restrict__ dinv,
    const ushort* __restrict__ xr, const float* __restrict__ b1,
    ushort* __restrict__ h1, int N) {
  GATHER_BODY(xl)
  {
    float di = dinv[node];
    float a0 = (eslot == 0) ? acc[0] : (eslot == 1) ? acc[2] : (eslot == 2) ? acc[4] : acc[6];
    float a1 = (eslot == 0) ? acc[1] : (eslot == 1) ? acc[3] : (eslot == 2) ? acc[5] : acc[7];
    const int d0 = col * 8 + eslot * 2;
    unsigned hv = *(const unsigned*)(xr + (size_t)node * DIM + d0);
    float2 bv = *(const float2*)(b1 + d0);
    float h0 = fmaxf(a0 * di + __uint_as_float(hv << 16) + bv.x, 0.f);
    float h1v = fmaxf(a1 * di + __uint_as_float(hv & 0xFFFF0000u) + bv.y, 0.f);
    *(unsigned*)(h1 + (size_t)node * DIM + d0) =
        (unsigned)f2bf(h0) | ((unsigned)f2bf(h1v) << 16);
  }
}

// ---- gather2: agg(h1l) -> h2=relu(.+h1r) -> lin3 dot -> y[N][4] (R9/R10-proven) ----
__global__ __launch_bounds__(256) void gather2_kernel(
    const ushort* __restrict__ h1l, const int* __restrict__ csr_src,
    const unsigned* __restrict__ off, const float* __restrict__ dinv,
    const ushort* __restrict__ h1r, const float* __restrict__ W3l,
    const float* __restrict__ W3r, float* __restrict__ y, int N) {
  GATHER_BODY(h1l)
  {
    float di = dinv[node];
    float a0 = (eslot == 0) ? acc[0] : (eslot == 1) ? acc[2] : (eslot == 2) ? acc[4] : acc[6];
    float a1 = (eslot == 0) ? acc[1] : (eslot == 1) ? acc[3] : (eslot == 2) ? acc[5] : acc[7];
    const int d0 = col * 8 + eslot * 2;
    unsigned hv = *(const unsigned*)(h1r + (size_t)node * DIM + d0);
    float h0 = fmaxf(a0 * di + __uint_as_float(hv << 16), 0.f);
    float h1v = fmaxf(a1 * di + __uint_as_float(hv & 0xFFFF0000u), 0.f);
    float4 wl = *(const float4*)(W3l + (size_t)d0 * 2);  // rows d0, d0+1
    float4 wr = *(const float4*)(W3r + (size_t)d0 * 2);
    float y0 = h0 * wl.x + h1v * wl.z;
    float y1 = h0 * wl.y + h1v * wl.w;
    float y2 = h0 * wr.x + h1v * wr.z;
    float y3 = h0 * wr.y + h1v * wr.w;
#pragma unroll
    for (int o = 1; o < 64; o <<= 1) {
      y0 += __shfl_xor(y0, o, 64);
      y1 += __shfl_xor(y1, o, 64);
      y2 += __shfl_xor(y2, o, 64);
      y3 += __shfl_xor(y3, o, 64);
    }
    if (lane == 0) *(float4*)(y + (size_t)node * 4) = make_float4(y0, y1, y2, y3);
  }
}

// ---- gemm1_dual: xl = x@W1l, xr = x@W1r (fp32 A staged->bf16; raw outputs) ----
// Shape = gemm2_dual (2 stage rounds, one A read, dual B, LDS-staged epilogue).
__global__ __launch_bounds__(256) void gemm1_dual_kernel(
    const float* __restrict__ x, const ushort* __restrict__ tabs1,
    ushort* __restrict__ xl, ushort* __restrict__ xr, int N) {
  __shared__ ushort L[3 * 128 * 64];  // 48 KB: As | Bs0 (W1l) | Bs1 (W1r)
  ushort* As = L;
  ushort* Bs0 = L + 8192;
  ushort* Bs1 = L + 16384;
  const int tid = threadIdx.x;
  const int bm = blockIdx.x * 128;
  const int wave = tid >> 6;
  const int lane = tid & 63;
  const int l15 = lane & 15;
  const int quad = lane >> 4;
  const int wm = wave >> 1;
  const int wn = wave & 1;

  f32x4 accl[4][4], accr[4][4];
#pragma unroll
  for (int i = 0; i < 4; ++i)
#pragma unroll
    for (int j = 0; j < 4; ++j) {
      accl[i][j] = (f32x4){0.f, 0.f, 0.f, 0.f};
      accr[i][j] = (f32x4){0.f, 0.f, 0.f, 0.f};
    }

  for (int g = 0; g < 2; ++g) {
    const int kt = g << 6;
    __syncthreads();
#pragma unroll
    for (int c = 0; c < 4; ++c) {
      int flat = c * 256 + tid;
      int row = flat >> 3;
      int kg = flat & 7;
      int swz = (kg ^ (row & 7)) << 3;
      int grow = bm + row;
      if (grow >= N) grow = N - 1;
      const float* xp = x + (size_t)grow * DIM + kt + kg * 8;
      float4 va = *(const float4*)(xp);
      float4 vb = *(const float4*)(xp + 4);
      int4 pk4;
      pk4.x = (int)((unsigned)f2bf(va.x) | ((unsigned)f2bf(va.y) << 16));
      pk4.y = (int)((unsigned)f2bf(va.z) | ((unsigned)f2bf(va.w) << 16));
      pk4.z = (int)((unsigned)f2bf(vb.x) | ((unsigned)f2bf(vb.y) << 16));
      pk4.w = (int)((unsigned)f2bf(vb.z) | ((unsigned)f2bf(vb.w) << 16));
      *(int4*)(&As[row * 64 + swz]) = pk4;
      *(int4*)(&Bs0[row * 64 + swz]) = *(const int4*)(tabs1 + (size_t)row * DIM + kt + kg * 8);
      *(int4*)(&Bs1[row * 64 + swz]) =
          *(const int4*)(tabs1 + 16384 + (size_t)row * DIM + kt + kg * 8);
    }
    __syncthreads();
#pragma unroll
    for (int ks = 0; ks < 2; ++ks) {
      bf16x8 af[4], bl[4], br[4];
      int kg = (ks << 2) + quad;
#pragma unroll
      for (int i = 0; i < 4; ++i) {
        int ar = (wm << 6) + (i << 4) + l15;
        af[i] = *(const bf16x8*)(&As[ar * 64 + ((kg ^ (ar & 7)) << 3)]);
        int nr = (wn << 6) + (i << 4) + l15;
        bl[i] = *(const bf16x8*)(&Bs0[nr * 64 + ((kg ^ (nr & 7)) << 3)]);
        br[i] = *(const bf16x8*)(&Bs1[nr * 64 + ((kg ^ (nr & 7)) << 3)]);
      }
#pragma unroll
      for (int i = 0; i < 4; ++i)
#pragma unroll
        for (int j = 0; j < 4; ++j) {
          accl[i][j] = __builtin_amdgcn_mfma_f32_16x16x32_bf16(af[i], bl[j], accl[i][j], 0, 0, 0);
          accr[i][j] = __builtin_amdgcn_mfma_f32_16x16x32_bf16(af[i], br[j], accr[i][j], 0, 0, 0);
        }
    }
  }

  // epilogue: restage each mat through L (32 KB) -> coalesced int4 writes (raw, no bias)
#pragma unroll
  for (int m = 0; m < 2; ++m) {
    __syncthreads();
#pragma unroll
    for (int i = 0; i < 4; ++i)
#pragma unroll
      for (int j = 0; j < 4; ++j)
#pragma unroll
        for (int r = 0; r < 4; ++r) {
          int row = (wm << 6) + (i << 4) + (quad << 2) + r;
          int colc = (wn << 6) + (j << 4) + l15;
          L[row * 128 + colc] = f2bf(m ? accr[i][j][r] : accl[i][j][r]);
        }
    __syncthreads();
    ushort* out = m ? xr : xl;
#pragma unroll
    for (int c = 0; c < 8; ++c) {
      int flat = c * 256 + tid;  // int4 id 0..2047
      int row = flat >> 4;
      int grow = bm + row;
      if (grow < N)
        *(int4*)(out + (size_t)grow * DIM + (flat & 15) * 8) = *(const int4*)(&L[flat * 8]);
    }
  }
}

// ---- gemm2_dual: h1l = h1@W2l, h1r = h1@W2r + b2 (R8/R10-proven) ----
__global__ __launch_bounds__(256) void gemm2_dual_kernel(
    const ushort* __restrict__ h1, const ushort* __restrict__ tabs2,
    const float* __restrict__ b2, ushort* __restrict__ h1l, ushort* __restrict__ h1r, int N) {
  __shared__ ushort L[3 * 128 * 64];  // 48 KB: As | Bs0 (W2l) | Bs1 (W2r)
  ushort* As = L;
  ushort* Bs0 = L + 8192;
  ushort* Bs1 = L + 16384;
  const int tid = threadIdx.x;
  const int bm = blockIdx.x * 128;
  const int wave = tid >> 6;
  const int lane = tid & 63;
  const int l15 = lane & 15;
  const int quad = lane >> 4;
  const int wm = wave >> 1;
  const int wn = wave & 1;

  f32x4 accl[4][4], accr[4][4];
#pragma unroll
  for (int i = 0; i < 4; ++i)
#pragma unroll
    for (int j = 0; j < 4; ++j) {
      accl[i][j] = (f32x4){0.f, 0.f, 0.f, 0.f};
      accr[i][j] = (f32x4){0.f, 0.f, 0.f, 0.f};
    }

  for (int g = 0; g < 2; ++g) {
    const int kt = g << 6;
    __syncthreads();
#pragma unroll
    for (int c = 0; c < 4; ++c) {
      int flat = c * 256 + tid;
      int row = flat >> 3;
      int kg = flat & 7;
      int swz = (kg ^ (row & 7)) << 3;
      int grow = bm + row;
      if (grow >= N) grow = N - 1;
      *(int4*)(&As[row * 64 + swz]) = *(const int4*)(h1 + (size_t)grow * DIM + kt + kg * 8);
      *(int4*)(&Bs0[row * 64 + swz]) = *(const int4*)(tabs2 + (size_t)row * DIM + kt + kg * 8);
      *(int4*)(&Bs1[row * 64 + swz]) =
          *(const int4*)(tabs2 + 16384 + (size_t)row * DIM + kt + kg * 8);
    }
    __syncthreads();
#pragma unroll
    for (int ks = 0; ks < 2; ++ks) {
      bf16x8 af[4], bl[4], br[4];
      int kg = (ks << 2) + quad;
#pragma unroll
      for (int i = 0; i < 4; ++i) {
        int ar = (wm << 6) + (i << 4) + l15;
        af[i] = *(const bf16x8*)(&As[ar * 64 + ((kg ^ (ar & 7)) << 3)]);
        int nr = (wn << 6) + (i << 4) + l15;
        bl[i] = *(const bf16x8*)(&Bs0[nr * 64 + ((kg ^ (nr & 7)) << 3)]);
        br[i] = *(const bf16x8*)(&Bs1[nr * 64 + ((kg ^ (nr & 7)) << 3)]);
      }
#pragma unroll
      for (int i = 0; i < 4; ++i)
#pragma unroll
        for (int j = 0; j < 4; ++j) {
          accl[i][j] = __builtin_amdgcn_mfma_f32_16x16x32_bf16(af[i], bl[j], accl[i][j], 0, 0, 0);
          accr[i][j] = __builtin_amdgcn_mfma_f32_16x16x32_bf16(af[i], br[j], accr[i][j], 0, 0, 0);
        }
    }
  }

  float bv[4];
#pragma unroll
  for (int j = 0; j < 4; ++j) bv[j] = b2[(wn << 6) + (j << 4) + l15];

  // epilogue: restage each mat through L[0..16383] (32 KB) -> coalesced int4 writes
#pragma unroll
  for (int m = 0; m < 2; ++m) {
    __syncthreads();
#pragma unroll
    for (int i = 0; i < 4; ++i)
#pragma unroll
      for (int j = 0; j < 4; ++j)
#pragma unroll
        for (int r = 0; r < 4; ++r) {
          int row = (wm << 6) + (i << 4) + (quad << 2) + r;
          int colc = (wn << 6) + (j << 4) + l15;
          float v = m ? (accr[i][j][r] + bv[j]) : accl[i][j][r];
          L[row * 128 + colc] = f2bf(v);
        }
    __syncthreads();
    ushort* out = m ? h1r : h1l;
#pragma unroll
    for (int c = 0; c < 8; ++c) {
      int flat = c * 256 + tid;  // int4 id 0..2047
      int row = flat >> 4;
      int grow = bm + row;
      if (grow < N)
        *(int4*)(out + (size_t)grow * DIM + (flat & 15) * 8) = *(const int4*)(&L[flat * 8]);
    }
  }
}

// ---- layer 3: 2-dim CSR gather + bias + relu + log_softmax ----
__global__ __launch_bounds__(256) void final3_kernel(const float* __restrict__ y,
                                                     const int* __restrict__ csr_src,
                                                     const unsigned* __restrict__ off,
                                                     const float* __restrict__ dinv,
                                                     const float* __restrict__ b3,
                                                     float* __restrict__ out, int N) {
  int n = blockIdx.x * 256 + threadIdx.x;
  if (n >= N) return;
  unsigned beg = off[n], end = off[n + 1];
  float s0 = 0.f, s1 = 0.f;
  for (unsigned e = beg; e < end; ++e) {
    int s = csr_src[e];
    float2 v = *reinterpret_cast<const float2*>(&y[(size_t)s * 4]);
    s0 += v.x; s1 += v.y;
  }
  float di = dinv[n];
  float o0 = fmaxf(s0 * di + y[(size_t)n * 4 + 2] + b3[0], 0.f);
  float o1 = fmaxf(s1 * di + y[(size_t)n * 4 + 3] + b3[1], 0.f);
  float m = fmaxf(o0, o1);
  float l = m + logf(expf(o0 - m) + expf(o1 - m));
  out[n * 2 + 0] = o0 - l;
  out[n * 2 + 1] = o1 - l;
}

extern "C" void kernel_launch(void* const* d_in, const int* in_sizes, int n_in,
                              void* d_out, int out_size, void* d_ws, size_t ws_size,
                              hipStream_t stream) {
  const float* x   = (const float*)d_in[0];
  const int*   ei  = (const int*)d_in[1];
  const float* W1l = (const float*)d_in[2];
  const float* W1r = (const float*)d_in[3];
  const float* b1  = (const float*)d_in[4];
  const float* W2l = (const float*)d_in[5];
  const float* W2r = (const float*)d_in[6];
  const float* b2  = (const float*)d_in[7];
  const float* W3l = (const float*)d_in[8];
  const float* W3r = (const float*)d_in[9];
  const float* b3  = (const float*)d_in[10];

  const int N = in_sizes[0] / DIM;  // 100000
  const int E = in_sizes[1] / 2;    // 1600000
  const int* src = ei;
  const int* dst = ei + E;

  const int NBUCK = (N + 127) >> 7;     // 782 buckets (128 nodes each)
  const int NB    = (E + 2047) / 2048;  // 782 count/scatter blocks

  char* ws = (char*)d_ws;
  size_t off_b = 0;
  auto alloc = [&](size_t bytes) {
    void* p = ws + off_b;
    off_b = (off_b + bytes + 255) & ~(size_t)255;
    return p;
  };
  unsigned* counts  = (unsigned*)alloc((size_t)NB * NBUCK * 4);  // 2.45 MB
  unsigned* totals  = (unsigned*)alloc((size_t)(NBUCK + 1) * 4);
  // shared_ region (25.6 MB): pairs (read last by fine) -> xl (gemm1_dual writes
  // after fine; read last by gather1) -> h1l (gemm2_dual writes after gather1).
  void*     shared_ = alloc((size_t)N * DIM * 2);
  unsigned* pairs   = (unsigned*)shared_;
  ushort*   xl      = (ushort*)shared_;
  ushort*   h1l     = (ushort*)shared_;
  int*      csr_src = (int*)alloc((size_t)E * 4);
  unsigned* offs    = (unsigned*)alloc((size_t)(N + 1) * 4);
  float*    dinv    = (float*)alloc((size_t)N * 4);
  // xr region: xr (gemm1_dual; read last by gather1) -> h1r (gemm2_dual writes after).
  ushort*   xr      = (ushort*)alloc((size_t)N * DIM * 2);
  ushort*   h1r     = xr;
  ushort*   h1      = (ushort*)alloc((size_t)N * DIM * 2);
  ushort*   tabs    = (ushort*)alloc((size_t)4 * 16384 * 2);
  float*    y       = (float*)alloc((size_t)N * 4 * 4);
  // total ~ 88 MB

  // ---- CSR build (no global atomics, no memset) ----
  count_wsplit_kernel<<<NB + 256, 256, 0, stream>>>(dst, counts, E, NB, NBUCK,
                                                    W1l, W1r, W2l, W2r, tabs);
  colscan_kernel<<<(NBUCK + 3) / 4, 256, 0, stream>>>(counts, totals, NB, NBUCK);
  totscan_kernel<<<1, 256, 0, stream>>>(totals, NBUCK, E);
  cscatter_kernel<<<NB, 256, 0, stream>>>(src, dst, counts, totals, pairs, E, NBUCK);
  fine_kernel<<<NBUCK, 256, 0, stream>>>(pairs, totals, csr_src, offs, dinv, N, NBUCK, E);

  const ushort* tabs1 = tabs;          // W1l | W1r  [n][k] bf16
  const ushort* tabs2 = tabs + 32768;  // W2l | W2r
  const int G = (N + 127) / 128;
  const int gather_grid = (N + 3) / 4;  // one wave per node

  // ---- layer 1 via linearity: xl = x@W1l, xr = x@W1r (x cast during staging) ----
  gemm1_dual_kernel<<<G, 256, 0, stream>>>(x, tabs1, xl, xr, N);
  // ---- layer 1 epilogue: h1 = relu(mean_agg(xl) + xr + b1) ----
  gather1_kernel<<<gather_grid, 256, 0, stream>>>(xl, csr_src, offs, dinv, xr, b1, h1, N);
  // ---- layer 2 via linearity: h1l = h1@W2l, h1r = h1@W2r + b2 (h1 read once) ----
  gemm2_dual_kernel<<<G, 256, 0, stream>>>(h1, tabs2, b2, h1l, h1r, N);
  // ---- layer 2 epilogue + lin3: h2 = relu(mean_agg(h1l) + h1r); y = h2@[W3l|W3r] ----
  gather2_kernel<<<gather_grid, 256, 0, stream>>>(h1l, csr_src, offs, dinv, h1r, W3l, W3r, y, N);
  // ---- layer 3 ----
  final3_kernel<<<(N + 255) / 256, 256, 0, stream>>>(y, csr_src, offs, dinv, b3, (float*)d_out, N);
}